// Round 7
// baseline (29.238 us; speedup 1.0000x reference)
//
#include <hip/hip_runtime.h>

// NuFACoef: out[b] = sum_{i,j} coef[i][j] * trace_ij / 16^(i+j+2),
// trace_ij = sum_k colsum(x^(i+2))[k]^(j+1); colsum chain u_{m+1} = u_m @ x.
//
// R7: break the burst->compute lockstep. Each wave owns a private 16KB LDS
// slot and NB=4 sequential batches. Loop: vmcnt(0) (slot ready) -> drain
// slot->regs (16 conflict-free ds_read_b128) -> lgkmcnt(0) -> issue
// global_load_lds stage of the NEXT batch into the same slot (fire-and-
// forget, no VGPR landing) -> compute current batch. Memory demand is
// continuous for the whole kernel; zero barriers (slots are wave-private).
// Grid 1024 blocks x 2 waves, 33KB LDS/block -> 4 blocks/CU, all resident.

#define NB 4   // batches per wave

typedef float vf4 __attribute__((ext_vector_type(4)));

__device__ __forceinline__ vf4 xor_reduce_rg(vf4 v) {
    v.x += __shfl_xor(v.x, 16, 64); v.y += __shfl_xor(v.y, 16, 64);
    v.z += __shfl_xor(v.z, 16, 64); v.w += __shfl_xor(v.w, 16, 64);
    v.x += __shfl_xor(v.x, 32, 64); v.y += __shfl_xor(v.y, 32, 64);
    v.z += __shfl_xor(v.z, 32, 64); v.w += __shfl_xor(v.w, 32, 64);
    return v;
}

// Stage one 16KB batch: 16 x global_load_lds width=16. LDS dest is
// wave-uniform base + lane*16 (linear), global src is per-lane.
__device__ __forceinline__ void stage_batch(const float* g, float* ls, int lane) {
    #pragma unroll
    for (int i = 0; i < 16; ++i) {
        __builtin_amdgcn_global_load_lds(
            (const __attribute__((address_space(1))) void*)(g + i * 256 + lane * 4),
            (__attribute__((address_space(3))) void*)(ls + i * 256),
            16, 0, 0);
    }
}

__global__ __launch_bounds__(128) void nufa_kernel(
    const float* __restrict__ x, const float* __restrict__ coef,
    float* __restrict__ out, int B)
{
    __shared__ float slot[2][4096];   // 16KB per wave
    __shared__ float us[2][4][64];    // per-wave u broadcast slots

    const int w    = threadIdx.x >> 6;
    const int lane = threadIdx.x & 63;
    const int rg   = lane >> 4;   // lane rows: 4i + rg, i = 0..15
    const int cg   = lane & 15;   // cols 4cg..4cg+3
    const int b0   = (blockIdx.x * 2 + w) * NB;
    if (b0 >= B) return;

    float* ls = &slot[w][0];
    const float* xb = x + (size_t)b0 * 4096;

    // cs[i][j] = coef[i][j] / 16^(i+j+2)  (uniform -> scalar path)
    float cs[4][4];
    #pragma unroll
    for (int i = 0; i < 4; ++i)
        #pragma unroll
        for (int j = 0; j < 4; ++j)
            cs[i][j] = coef[i * 4 + j] * (1.0f / (float)(1ull << (4 * (i + j + 2))));

    stage_batch(xb, ls, lane);   // prologue: batch 0 in flight

    #pragma unroll
    for (int it = 0; it < NB; ++it) {
        // slot ready?
        asm volatile("s_waitcnt vmcnt(0)" ::: "memory");
        __builtin_amdgcn_sched_barrier(0);

        // drain slot -> regs: lane t reads f4[64i+t] -> rows 4i+rg, cols of cg.
        vf4 xr[16];
        #pragma unroll
        for (int k = 0; k < 16; ++k)
            xr[k] = *reinterpret_cast<const vf4*>(ls + k * 256 + lane * 4);

        // drain complete -> slot free for the next batch
        asm volatile("s_waitcnt lgkmcnt(0)" ::: "memory");
        __builtin_amdgcn_sched_barrier(0);
        if (it + 1 < NB) stage_batch(xb + (size_t)(it + 1) * 4096, ls, lane);

        // ---- compute batch it (loads for it+1 in flight underneath) ----
        // u1 = colsum(x): own-rows partial, then reduce over rg groups.
        vf4 u = xr[0];
        #pragma unroll
        for (int k = 1; k < 16; ++k) u += xr[k];
        u = xor_reduce_rg(u);   // component c = colsum(col 4cg+c)

        if (rg == 0) *reinterpret_cast<vf4*>(&us[w][0][4 * cg]) = u;

        float contrib = 0.f;
        #pragma unroll
        for (int m = 0; m < 4; ++m) {
            // acc[c] = sum_i u[4i+rg] * x[4i+rg][c]; u[4i+rg] = us[m][4i+rg]
            // (wave-private LDS, compiler-ordered lgkmcnt; 16-lane broadcast).
            const float* uslot = &us[w][m][rg];
            vf4 acc = {0.f, 0.f, 0.f, 0.f};
            #pragma unroll
            for (int i = 0; i < 16; ++i) acc += uslot[4 * i] * xr[i];
            u = xor_reduce_rg(acc);   // colsum(x^(m+2))
            if (m < 3 && rg == 0)
                *reinterpret_cast<vf4*>(&us[w][m + 1][4 * cg]) = u;

            #pragma unroll
            for (int c = 0; c < 4; ++c) {
                const float v1 = (c == 0) ? u.x : (c == 1) ? u.y
                               : (c == 2) ? u.z : u.w;
                const float v2 = v1 * v1;
                const float v3 = v2 * v1;
                const float v4 = v2 * v2;
                contrib += cs[m][0] * v1 + cs[m][1] * v2
                         + cs[m][2] * v3 + cs[m][3] * v4;
            }
        }

        // contrib depends only on cg: reduce the 16 cg lanes.
        #pragma unroll
        for (int d = 1; d < 16; d <<= 1) contrib += __shfl_xor(contrib, d, 64);
        if (lane == 0) out[b0 + it] = contrib;
    }
}

extern "C" void kernel_launch(void* const* d_in, const int* in_sizes, int n_in,
                              void* d_out, int out_size, void* d_ws, size_t ws_size,
                              hipStream_t stream) {
    const float* x    = (const float*)d_in[0];
    const float* coef = (const float*)d_in[1];
    float* out        = (float*)d_out;
    const int B = in_sizes[0] / 4096;                    // 64*64 per batch
    const int waves  = (B + NB - 1) / NB;                // 1 wave per NB batches
    const int blocks = (waves + 1) / 2;                  // 2 waves per block
    nufa_kernel<<<blocks, 128, 0, stream>>>(x, coef, out, B);
}

// Round 8
// 26.294 us; speedup vs baseline: 1.1120x; 1.1120x over previous
//
#include <hip/hip_runtime.h>

// NuFACoef: out[b] = sum_{i,j} coef[i][j] * trace_ij / 16^(i+j+2),
// trace_ij = sum_k colsum(x^(i+2))[k]^(j+1); colsum chain u_{m+1} = u_m @ x.
//
// R8: zero-DS-pipe variant. Lane c owns full column c (64 VGPRs; loads are
// 64 x 256B perfectly-coalesced dword instrs). u[c] = in-lane column sum
// (pure VALU). The u-broadcast for u_new[c] = sum_i u[i]*x[i][c] uses
// v_readlane with compile-time lane indices -> scalar operand, no LDS/DS.
// Only 6 shfl_xor per batch remain (final scalar reduce).

__device__ __forceinline__ float rdlane(float v, int i) {
    return __int_as_float(__builtin_amdgcn_readlane(__float_as_int(v), i));
}

__global__ __launch_bounds__(256) void nufa_kernel(
    const float* __restrict__ x, const float* __restrict__ coef,
    float* __restrict__ out, int B)
{
    const int wave = threadIdx.x >> 6;
    const int lane = threadIdx.x & 63;
    const int b    = blockIdx.x * 4 + wave;
    if (b >= B) return;   // B divisible by 4: whole waves stay active

    // lane c holds column c: x[i][c], i = 0..63. Instr i covers
    // bytes [4096b + 256i, +256) -> perfectly coalesced.
    const float* xb = x + (size_t)b * 4096 + lane;
    float xr[64];
    #pragma unroll
    for (int i = 0; i < 64; ++i) xr[i] = xb[i * 64];

    // cs[m][j] = coef[m][j] / 16^(m+j+2)  (uniform -> scalar path)
    float cs[4][4];
    #pragma unroll
    for (int m = 0; m < 4; ++m)
        #pragma unroll
        for (int j = 0; j < 4; ++j)
            cs[m][j] = coef[m * 4 + j] * (1.0f / (float)(1ull << (4 * (m + j + 2))));

    // u = colsum(x)[c]: in-lane sum, 8 accumulators for ILP.
    float s0 = xr[0], s1 = xr[1], s2 = xr[2], s3 = xr[3],
          s4 = xr[4], s5 = xr[5], s6 = xr[6], s7 = xr[7];
    #pragma unroll
    for (int i = 8; i < 64; i += 8) {
        s0 += xr[i];     s1 += xr[i + 1]; s2 += xr[i + 2]; s3 += xr[i + 3];
        s4 += xr[i + 4]; s5 += xr[i + 5]; s6 += xr[i + 6]; s7 += xr[i + 7];
    }
    float u = ((s0 + s1) + (s2 + s3)) + ((s4 + s5) + (s6 + s7));

    float contrib = 0.f;
    #pragma unroll
    for (int m = 0; m < 4; ++m) {
        // u_new[c] = sum_i u[i] * x[i][c]; u[i] via readlane (compile-time
        // lane index, wave-uniform scalar) -> zero DS ops. 4 FMA chains.
        float a0 = 0.f, a1 = 0.f, a2 = 0.f, a3 = 0.f;
        #pragma unroll
        for (int i = 0; i < 64; i += 4) {
            a0 = __builtin_fmaf(rdlane(u, i + 0), xr[i + 0], a0);
            a1 = __builtin_fmaf(rdlane(u, i + 1), xr[i + 1], a1);
            a2 = __builtin_fmaf(rdlane(u, i + 2), xr[i + 2], a2);
            a3 = __builtin_fmaf(rdlane(u, i + 3), xr[i + 3], a3);
        }
        u = (a0 + a1) + (a2 + a3);   // colsum(x^(m+2))[c]

        const float v1 = u, v2 = u * u, v3 = v2 * u, v4 = v2 * v2;
        contrib += cs[m][0] * v1 + cs[m][1] * v2 + cs[m][2] * v3 + cs[m][3] * v4;
    }

    // Sum over the 64 columns (lanes): the only cross-lane ops in the kernel.
    #pragma unroll
    for (int d = 1; d < 64; d <<= 1) contrib += __shfl_xor(contrib, d, 64);
    if (lane == 0) out[b] = contrib;
}

extern "C" void kernel_launch(void* const* d_in, const int* in_sizes, int n_in,
                              void* d_out, int out_size, void* d_ws, size_t ws_size,
                              hipStream_t stream) {
    const float* x    = (const float*)d_in[0];
    const float* coef = (const float*)d_in[1];
    float* out        = (float*)d_out;
    const int B = in_sizes[0] / 4096;        // 64*64 per batch
    const int blocks = (B + 3) / 4;          // 1 wave per batch, 4 waves/block
    nufa_kernel<<<blocks, 256, 0, stream>>>(x, coef, out, B);
}